// Round 6
// baseline (14.931 us; speedup 1.0000x reference)
//
#include <hip/hip_runtime.h>
#include <math.h>

// Problem constants (fixed by the reference): B=2, N=64, CI=CO=32
#define NZ 2
#define NN 64
#define NCI 32
#define NCO 32
#define SLICES 32              // k1 blocks per z; each covers 128 (c,d) pairs
// ws: folded partials part[z][sl][224]  (224 = QA[96] QB[96] gam[32])

__device__ __forceinline__ void ld4(const float* __restrict__ p, float* d) {
    const float4 v = *(const float4*)p;
    d[0] = v.x; d[1] = v.y; d[2] = v.z; d[3] = v.w;
}

// Math (everything linear in rel = r_b - r_a):
//   ft[j]   = sum_{c,d} f[c,d,j]
//   Gs[x,j] = sum_{c,d} g_c[x] * f[c,d,j]
//   Gd[x,j] = sum_{c,d} g_d[x] * f[c,d,j]
//   Qm[x,i] = sum_j Wm[x,i,j] * ft[j]
//   QA = scale*(Q1+Q2+Q3) (coeff of -g_a[x]);  QB = scale*(Q1-Q4-Q5) (+g_b[x])
//   gam[i]  = scale * sum_{x,j} [(W2+W4-W6)*Gs + (W3+W5+W6)*Gd]
//   out[z,a,b,i] = gam[i] + sum_x (g_b[x]*QB[x,i] - g_a[x]*QA[x,i])
// The fold is linear in (ft,Gs,Gd), so each k1 block folds its own slice
// partial and k2 just sums folded partials.

// ---------------------------------------------------------------------------
// k1: 64 blocks x 1024 threads. Block = 128-pair slice of one z.
//   One float4 feature load per thread (features read exactly once grid-wide),
//   wave shfl-reduce, 768-thread parallel W-fold, 224-float partial store.
// ---------------------------------------------------------------------------
__global__ __launch_bounds__(1024) void k_part(const float* __restrict__ feat,
                                               const float* __restrict__ geom,
                                               const float* __restrict__ W,
                                               const int* __restrict__ nnp,
                                               float* __restrict__ part) {
    const int bid  = blockIdx.x;
    const int z    = bid >> 5;      // 0..1
    const int s    = bid & 31;      // slice 0..31
    const int tid  = threadIdx.x;
    const int lane = tid & 63;
    const int wv   = tid >> 6;      // 0..15
    const int cg   = tid & 7;       // channel group (j0 = cg*4)
    const int pr   = tid >> 3;      // pair-in-slice 0..127

    __shared__ float gsh[NN * 3];
    __shared__ float wred[16][7][32];
    __shared__ float sacc[7][32];
    __shared__ float gred[3][32];

    if (tid < NN * 3) gsh[tid] = geom[z * NN * 3 + tid];
    __syncthreads();

    // ---- slice reduction: one float4 load per thread
    const int p = s * 128 + pr;     // global pair 0..4095
    const int c = p >> 6, d = p & 63;
    float f[4];
    ld4(feat + ((size_t)z * 4096 + p) * NCI + cg * 4, f);

    float v[7][4];
    #pragma unroll
    for (int k = 0; k < 4; ++k) {
        v[0][k] = f[k];
        #pragma unroll
        for (int x = 0; x < 3; ++x) {
            v[1 + x][k] = gsh[c * 3 + x] * f[k];
            v[4 + x][k] = gsh[d * 3 + x] * f[k];
        }
    }
    // pr low bits live in lane bits 3..5 -> butterfly over 8,16,32
    #pragma unroll
    for (int q = 0; q < 7; ++q)
        #pragma unroll
        for (int k = 0; k < 4; ++k) {
            float t = v[q][k];
            t += __shfl_xor(t, 8);
            t += __shfl_xor(t, 16);
            t += __shfl_xor(t, 32);
            v[q][k] = t;
        }
    if (lane < 8) {
        #pragma unroll
        for (int q = 0; q < 7; ++q)
            #pragma unroll
            for (int k = 0; k < 4; ++k) wred[wv][q][lane * 4 + k] = v[q][k];
    }
    __syncthreads();
    if (tid < 224) {
        const int q = tid >> 5, j = tid & 31;
        float sum = 0.f;
        #pragma unroll
        for (int g = 0; g < 16; ++g) sum += wred[g][q][j];
        sacc[q][j] = sum;
    }
    __syncthreads();

    // n_norm: Python scalar -> 1-elem array; hedge int32 vs float32 bits.
    const int vn = *nnp;
    const float nnv = (vn > 0 && vn < (1 << 23)) ? (float)vn : __int_as_float(vn);
    const float scale = 1.0f / sqrtf(6.0f * nnv * nnv);

    // ---- parallel W-fold over 768 threads = (x, i, jg); shfl-reduce jg.
    float* slot = part + (size_t)bid * 224;
    if (tid < 768) {
        const int x = tid >> 8, i = (tid >> 3) & 31, jg = tid & 7;
        const float* Wp = W + x * 6 * NCO * NCI + i * NCI + jg * 4;  // m stride 1024
        float w[6][4];
        #pragma unroll
        for (int m = 0; m < 6; ++m) ld4(Wp + m * 1024, w[m]);
        float q1 = 0.f, q23 = 0.f, q45 = 0.f, gp = 0.f;
        #pragma unroll
        for (int k = 0; k < 4; ++k) {
            const int j = jg * 4 + k;
            const float ftj = sacc[0][j];
            const float gsj = sacc[1 + x][j];
            const float gdj = sacc[4 + x][j];
            q1  = fmaf(w[0][k], ftj, q1);
            q23 = fmaf(w[1][k] + w[2][k], ftj, q23);
            q45 = fmaf(w[3][k] + w[4][k], ftj, q45);
            gp  = fmaf(w[1][k] + w[3][k] - w[5][k], gsj, gp);
            gp  = fmaf(w[2][k] + w[4][k] + w[5][k], gdj, gp);
        }
        #pragma unroll
        for (int m = 1; m <= 4; m <<= 1) {
            q1  += __shfl_xor(q1, m);
            q23 += __shfl_xor(q23, m);
            q45 += __shfl_xor(q45, m);
            gp  += __shfl_xor(gp, m);
        }
        if (jg == 0) {
            slot[x * 32 + i]      = scale * (q1 + q23);   // QA partial
            slot[96 + x * 32 + i] = scale * (q1 - q45);   // QB partial
            gred[x][i] = gp;
        }
    }
    __syncthreads();
    if (tid < 32)
        slot[192 + tid] = scale * (gred[0][tid] + gred[1][tid] + gred[2][tid]);
}

// ---------------------------------------------------------------------------
// k2: 64 blocks x 1024 threads. Sum the 32 folded partials for this z
// (8 loads/thread), then write 128 output rows (one float4 store/thread).
// ---------------------------------------------------------------------------
__global__ __launch_bounds__(1024) void k_out(const float* __restrict__ part,
                                              const float* __restrict__ geom,
                                              float* __restrict__ out) {
    const int bid = blockIdx.x;
    const int z   = bid >> 5;       // 0..1
    const int s   = bid & 31;       // output chunk 0..31
    const int tid = threadIdx.x;

    __shared__ float gsh[NN * 3];
    __shared__ float red4[4][224];
    __shared__ float stab[224];     // QA[96] QB[96] gam[32]

    if (tid < NN * 3) gsh[tid] = geom[z * NN * 3 + tid];

    // Phase A: table = sum of 32 slices. (e, sg): 8 loads each.
    if (tid < 896) {
        const int e = tid >> 2, sg = tid & 3;
        const float* pz = part + ((size_t)z * 32 + sg * 8) * 224 + e;
        float sum = 0.f;
        #pragma unroll
        for (int t = 0; t < 8; ++t) sum += pz[t * 224];
        red4[sg][e] = sum;
    }
    __syncthreads();
    if (tid < 224)
        stab[tid] = red4[0][tid] + red4[1][tid] + red4[2][tid] + red4[3][tid];
    __syncthreads();

    // Phase B: out[z,a,b,i] = gam + sum_x (g_b*QB - g_a*QA)
    const int cg = tid & 7, i0 = cg * 4;
    const int r  = tid >> 3;            // 0..127
    const int ab = s * 128 + r;
    const int a = ab >> 6, b = ab & 63;
    float o4[4];
    #pragma unroll
    for (int k = 0; k < 4; ++k) o4[k] = stab[192 + i0 + k];
    #pragma unroll
    for (int x = 0; x < 3; ++x) {
        const float gb = gsh[b * 3 + x], ga = gsh[a * 3 + x];
        #pragma unroll
        for (int k = 0; k < 4; ++k)
            o4[k] = fmaf(gb, stab[96 + x * 32 + i0 + k],
                         fmaf(-ga, stab[x * 32 + i0 + k], o4[k]));
    }
    float4 o; o.x = o4[0]; o.y = o4[1]; o.z = o4[2]; o.w = o4[3];
    *(float4*)(out + ((size_t)(z * 4096 + ab)) * NCI + i0) = o;
}

extern "C" void kernel_launch(void* const* d_in, const int* in_sizes, int n_in,
                              void* d_out, int out_size, void* d_ws, size_t ws_size,
                              hipStream_t stream) {
    const float* feat = (const float*)d_in[0];   // [2,64,64,32]
    const float* geom = (const float*)d_in[1];   // [2,64,3]
    const float* W    = (const float*)d_in[2];   // [3,6144]
    const int*   nnp  = (const int*)d_in[3];     // scalar n_norm

    float* part = (float*)d_ws;                  // [2][32][224] folded partials

    k_part<<<NZ * SLICES, 1024, 0, stream>>>(feat, geom, W, nnp, part);
    k_out<<<NZ * SLICES, 1024, 0, stream>>>(part, geom, (float*)d_out);
}